// Round 3
// baseline (185.650 us; speedup 1.0000x reference)
//
#include <hip/hip_runtime.h>
#include <hip/hip_cooperative_groups.h>
#include <math.h>

#define NB 32          // batch
#define N  128         // input spatial
#define TS 140         // target spatial
#define NSH1 13        // shifts per dim
#define NSH 169        // total shifts
#define NPIX 16384     // 128*128
#define TPLANE 19600   // 140*140
#define NBLK (14 * NB) // 448 blocks
#define NCHUNK (NB * NPIX / 256)  // 2048 gather chunks of 256 px

namespace cg = cooperative_groups;

__device__ inline float waveReduceSum(float v) {
#pragma unroll
    for (int o = 32; o > 0; o >>= 1) v += __shfl_down(v, o, 64);
    return v;
}

// Single cooperative kernel, grid (14, 32) x 256 threads.
// Phase 1: di in [0,13): C[b][di*13+dj] = sum x[b] * y[b] shifted; di==13: sa[b].
// grid.sync()
// Phase 2: grid-strided gather of winning windows (block-local redundant
//          argmax per chunk); block 0 also writes total loss to out[0].
__global__ __launch_bounds__(256) void k_fused(const float* __restrict__ x,
                                               const float* __restrict__ y,
                                               float* __restrict__ C,
                                               float* __restrict__ sa,
                                               float* __restrict__ out) {
    int di = blockIdx.x;
    int b  = blockIdx.y;
    int t  = threadIdx.x;
    __shared__ float ylds[N * TS];  // 71.68 KB
    __shared__ float sv[256];
    __shared__ int   si[256];
    __shared__ float red2[4];

    // ================= Phase 1 =================
    if (di == NSH1) {
        // self term (shift independent)
        const float* xb = x + (size_t)b * NPIX;
        float acc = 0.f;
        for (int k = t; k < NPIX / 4; k += 256) {
            float4 v = *reinterpret_cast<const float4*>(xb + k * 4);
#pragma unroll
            for (int u = 0; u < 4; u++) {
                float xv = (&v.x)[u];
                acc += fmaxf(xv, 0.f) + log1pf(__expf(-fabsf(xv)));
            }
        }
        float v = waveReduceSum(acc);
        int lane = t & 63, wid = t >> 6;
        if (lane == 0) red2[wid] = v;
        __syncthreads();
        if (t == 0) sa[b] = red2[0] + red2[1] + red2[2] + red2[3];
    } else {
        // correlation for one row-shift di, all 13 col-shifts
        const float* yb = y + (size_t)b * TPLANE + di * TS;  // 17920 floats
        for (int k = t; k < (N * TS) / 4; k += 256) {
            reinterpret_cast<float4*>(ylds)[k] = reinterpret_cast<const float4*>(yb)[k];
        }
        __syncthreads();

        const float* xb = x + (size_t)b * NPIX;
        float acc[NSH1];
#pragma unroll
        for (int d = 0; d < NSH1; d++) acc[d] = 0.f;

        for (int k = t; k < NPIX / 4; k += 256) {
            int r = k >> 5;            // 32 float4-chunks per row
            int c = (k & 31) << 2;
            float4 xv = *reinterpret_cast<const float4*>(xb + r * N + c);
            const float* yrow = ylds + r * TS + c;
            float yl[16];
#pragma unroll
            for (int q = 0; q < 4; q++) {
                float4 yv = *reinterpret_cast<const float4*>(yrow + q * 4);
                yl[q * 4 + 0] = yv.x; yl[q * 4 + 1] = yv.y;
                yl[q * 4 + 2] = yv.z; yl[q * 4 + 3] = yv.w;
            }
#pragma unroll
            for (int d = 0; d < NSH1; d++) {
                acc[d] += xv.x * yl[d] + xv.y * yl[d + 1] + xv.z * yl[d + 2] + xv.w * yl[d + 3];
            }
        }

        __shared__ float red[NSH1][4];
        int lane = t & 63, wid = t >> 6;
#pragma unroll
        for (int d = 0; d < NSH1; d++) {
            float v = waveReduceSum(acc[d]);
            if (lane == 0) red[d][wid] = v;
        }
        __syncthreads();
        if (t < NSH1) {
            C[(size_t)b * NSH + di * NSH1 + t] = red[t][0] + red[t][1] + red[t][2] + red[t][3];
        }
    }

    __threadfence();
    cg::this_grid().sync();

    // ================= Phase 2 =================
    int bid = b * 14 + di;  // 0..447

    if (bid == 0) {
        // total loss = sum_b (sa[b] - max_s C[b][s]) / 16384
        int bb = t >> 3, l8 = t & 7;   // 8 lanes per sample
        float mx = -INFINITY;
        for (int s = l8; s < NSH; s += 8) mx = fmaxf(mx, C[(size_t)bb * NSH + s]);
        mx = fmaxf(mx, __shfl_xor(mx, 1, 64));
        mx = fmaxf(mx, __shfl_xor(mx, 2, 64));
        mx = fmaxf(mx, __shfl_xor(mx, 4, 64));
        float contrib = (l8 == 0) ? (sa[bb] - mx) : 0.f;
        float s = waveReduceSum(contrib);
        int lane = t & 63, wid = t >> 6;
        if (lane == 0) red2[wid] = s;
        __syncthreads();
        if (t == 0) out[0] = (red2[0] + red2[1] + red2[2] + red2[3]) * (1.0f / 16384.0f);
    }

    for (int chunk = bid; chunk < NCHUNK; chunk += NBLK) {
        int gb   = chunk >> 6;        // sample
        int pblk = chunk & 63;        // 256-px block within sample

        // block-local argmax over C[gb] (first index on ties)
        float v = -INFINITY; int idx = 0x7fffffff;
        if (t < NSH) { v = C[(size_t)gb * NSH + t]; idx = t; }
        sv[t] = v; si[t] = idx;
        __syncthreads();
        for (int o = 128; o > 0; o >>= 1) {
            if (t < o) {
                float v2 = sv[t + o]; int i2 = si[t + o];
                if (v2 > sv[t] || (v2 == sv[t] && i2 < si[t])) { sv[t] = v2; si[t] = i2; }
            }
            __syncthreads();
        }
        int best = si[0];
        __syncthreads();   // protect sv/si for next chunk
        int i0 = best / NSH1, j0 = best % NSH1;

        int p = pblk * 256 + t;
        int r = p >> 7, c = p & 127;
        out[1 + (size_t)gb * NPIX + p] = y[(size_t)gb * TPLANE + (i0 + r) * TS + j0 + c];
    }
}

extern "C" void kernel_launch(void* const* d_in, const int* in_sizes, int n_in,
                              void* d_out, int out_size, void* d_ws, size_t ws_size,
                              hipStream_t stream) {
    const float* x = (const float*)d_in[0];   // [32,1,128,128] f32
    const float* y = (const float*)d_in[1];   // [32,1,140,140] f32
    float* out = (float*)d_out;               // [1 + 32*16384] f32
    float* ws = (float*)d_ws;

    float* C  = ws;            // 32*169 = 5408 floats
    float* sa = ws + 5408;     // 32 floats

    void* args[] = {(void*)&x, (void*)&y, (void*)&C, (void*)&sa, (void*)&out};
    hipLaunchCooperativeKernel((void*)k_fused, dim3(NSH1 + 1, NB), dim3(256),
                               args, 0, stream);
}

// Round 4
// 83.312 us; speedup vs baseline: 2.2284x; 2.2284x over previous
//
#include <hip/hip_runtime.h>
#include <math.h>

#define NB 32          // batch
#define N  128         // input spatial
#define TS 140         // target spatial
#define NSH1 13        // shifts per dim
#define NSH 169        // total shifts
#define NPIX 16384     // 128*128
#define TPLANE 19600   // 140*140

__device__ inline float waveReduceSum(float v) {
#pragma unroll
    for (int o = 32; o > 0; o >>= 1) v += __shfl_down(v, o, 64);
    return v;
}

// grid (14, 32):
//   di in [0,13): C[b][di*13+dj] = sum_{r,c} x[b][r][c] * y[b][r+di][c+dj]
//   di == 13:     sa[b] = sum relu(x) + log1p(exp(-|x|))
__global__ __launch_bounds__(256) void k_main(const float* __restrict__ x,
                                              const float* __restrict__ y,
                                              float* __restrict__ C,
                                              float* __restrict__ sa) {
    int di = blockIdx.x;
    int b  = blockIdx.y;
    int t  = threadIdx.x;
    __shared__ float ylds[N * TS];  // 71.68 KB

    if (di == NSH1) {
        // ---- self term (shift independent) ----
        const float* xb = x + (size_t)b * NPIX;
        float acc = 0.f;
        for (int k = t; k < NPIX / 4; k += 256) {
            float4 v = *reinterpret_cast<const float4*>(xb + k * 4);
#pragma unroll
            for (int u = 0; u < 4; u++) {
                float xv = (&v.x)[u];
                acc += fmaxf(xv, 0.f) + log1pf(__expf(-fabsf(xv)));
            }
        }
        float v = waveReduceSum(acc);
        int lane = t & 63, wid = t >> 6;
        if (lane == 0) ylds[wid] = v;
        __syncthreads();
        if (t == 0) sa[b] = ylds[0] + ylds[1] + ylds[2] + ylds[3];
        return;
    }

    // ---- correlation for one row-shift di, all 13 col-shifts ----
    const float* yb = y + (size_t)b * TPLANE + di * TS;  // 17920 contiguous floats
    for (int k = t; k < (N * TS) / 4; k += 256) {
        reinterpret_cast<float4*>(ylds)[k] = reinterpret_cast<const float4*>(yb)[k];
    }
    __syncthreads();

    const float* xb = x + (size_t)b * NPIX;
    float acc[NSH1];
#pragma unroll
    for (int d = 0; d < NSH1; d++) acc[d] = 0.f;

    for (int k = t; k < NPIX / 4; k += 256) {
        int r = k >> 5;            // 32 float4-chunks per row
        int c = (k & 31) << 2;
        float4 xv = *reinterpret_cast<const float4*>(xb + r * N + c);
        const float* yrow = ylds + r * TS + c;
        float yl[16];
#pragma unroll
        for (int q = 0; q < 4; q++) {
            float4 yv = *reinterpret_cast<const float4*>(yrow + q * 4);
            yl[q * 4 + 0] = yv.x; yl[q * 4 + 1] = yv.y;
            yl[q * 4 + 2] = yv.z; yl[q * 4 + 3] = yv.w;
        }
#pragma unroll
        for (int d = 0; d < NSH1; d++) {
            acc[d] += xv.x * yl[d] + xv.y * yl[d + 1] + xv.z * yl[d + 2] + xv.w * yl[d + 3];
        }
    }

    __shared__ float red[NSH1][4];
    int lane = t & 63, wid = t >> 6;
#pragma unroll
    for (int d = 0; d < NSH1; d++) {
        float v = waveReduceSum(acc[d]);
        if (lane == 0) red[d][wid] = v;
    }
    __syncthreads();
    if (t < NSH1) {
        C[(size_t)b * NSH + di * NSH1 + t] = red[t][0] + red[t][1] + red[t][2] + red[t][3];
    }
}

// grid (64, 32): per block: wave-0 argmax over C[b] (first-index tie-break),
// broadcast, gather 256 pixels. Block (0,0) also computes total loss.
__global__ __launch_bounds__(256) void k_out(const float* __restrict__ y,
                                             const float* __restrict__ C,
                                             const float* __restrict__ sa,
                                             float* __restrict__ out) {
    int b = blockIdx.y, t = threadIdx.x;
    __shared__ int bestSh;

    if (t < 64) {
        // lane handles indices {t, t+64, t+128} in increasing order
        const float* Cb = C + (size_t)b * NSH;
        float v = Cb[t]; int idx = t;
#pragma unroll
        for (int q = 1; q < 3; q++) {
            int i2 = t + q * 64;
            if (i2 < NSH) {
                float v2 = Cb[i2];
                if (v2 > v) { v = v2; idx = i2; }   // later index: only strict >
            }
        }
#pragma unroll
        for (int o = 1; o < 64; o <<= 1) {
            float v2 = __shfl_xor(v, o, 64);
            int   i2 = __shfl_xor(idx, o, 64);
            if (v2 > v || (v2 == v && i2 < idx)) { v = v2; idx = i2; }
        }
        if (t == 0) bestSh = idx;
    }
    __syncthreads();
    int best = bestSh;
    int i0 = best / NSH1, j0 = best % NSH1;

    int p = blockIdx.x * 256 + t;      // [0, 16384)
    int r = p >> 7, c = p & 127;
    out[1 + (size_t)b * NPIX + p] = y[(size_t)b * TPLANE + (i0 + r) * TS + j0 + c];

    if (blockIdx.x == 0 && b == 0) {
        // total loss = sum_b (sa[b] - max_s C[b][s]) / 16384
        int bb = t >> 3, l8 = t & 7;   // 8 lanes per sample
        float mx = -INFINITY;
        for (int s = l8; s < NSH; s += 8) mx = fmaxf(mx, C[(size_t)bb * NSH + s]);
        mx = fmaxf(mx, __shfl_xor(mx, 1, 64));
        mx = fmaxf(mx, __shfl_xor(mx, 2, 64));
        mx = fmaxf(mx, __shfl_xor(mx, 4, 64));
        float contrib = (l8 == 0) ? (sa[bb] - mx) : 0.f;
        float s = waveReduceSum(contrib);
        __shared__ float red2[4];
        int lane = t & 63, wid = t >> 6;
        if (lane == 0) red2[wid] = s;
        __syncthreads();
        if (t == 0) out[0] = (red2[0] + red2[1] + red2[2] + red2[3]) * (1.0f / 16384.0f);
    }
}

extern "C" void kernel_launch(void* const* d_in, const int* in_sizes, int n_in,
                              void* d_out, int out_size, void* d_ws, size_t ws_size,
                              hipStream_t stream) {
    const float* x = (const float*)d_in[0];   // [32,1,128,128] f32
    const float* y = (const float*)d_in[1];   // [32,1,140,140] f32
    float* out = (float*)d_out;               // [1 + 32*16384] f32
    float* ws = (float*)d_ws;

    float* C  = ws;            // 32*169 = 5408 floats
    float* sa = ws + 5408;     // 32 floats

    k_main<<<dim3(NSH1 + 1, NB), 256, 0, stream>>>(x, y, C, sa);
    k_out <<<dim3(NPIX / 256, NB), 256, 0, stream>>>(y, C, sa, out);
}